// Round 3
// baseline (225.138 us; speedup 1.0000x reference)
//
#include <hip/hip_runtime.h>
#include <hip/hip_bf16.h>

#define Bn 4096
#define Dk 1024
#define EPSF 1e-7f

typedef float f32x4 __attribute__((ext_vector_type(4)));
typedef float f32x16 __attribute__((ext_vector_type(16)));
typedef int i32x4 __attribute__((ext_vector_type(4)));
typedef int i32x8 __attribute__((ext_vector_type(8)));

__device__ __forceinline__ void async_copy16(const void* g, void* l) {
    __builtin_amdgcn_global_load_lds((__attribute__((address_space(1))) void*)(uintptr_t)g,
                                     (__attribute__((address_space(3))) void*)l, 16, 0, 0);
}

// -------- Kernel 1: L2-normalize -> fp8 e4m3 (x8 prescale), PLAIN row-major layout ----
__global__ __launch_bounds__(256)
void nrm_kernel(const float4* __restrict__ left, const float4* __restrict__ right,
                unsigned char* __restrict__ lnb8, unsigned char* __restrict__ rnb8,
                float* __restrict__ diag, float* __restrict__ rowsum,
                float* __restrict__ colsum)
{
    const int row = blockIdx.x;
    const int t = threadIdx.x;
    const int idx = row * (Dk / 4) + t;
    const float4 l = left[idx];
    const float4 r = right[idx];
    float sl = l.x * l.x + l.y * l.y + l.z * l.z + l.w * l.w;
    float sr = r.x * r.x + r.y * r.y + r.z * r.z + r.w * r.w;
    float slr = l.x * r.x + l.y * r.y + l.z * r.z + l.w * r.w;
    #pragma unroll
    for (int off = 1; off < 64; off <<= 1) {
        sl += __shfl_xor(sl, off);
        sr += __shfl_xor(sr, off);
        slr += __shfl_xor(slr, off);
    }
    __shared__ float red[3][4];
    const int wave = t >> 6, lane = t & 63;
    if (lane == 0) { red[0][wave] = sl; red[1][wave] = sr; red[2][wave] = slr; }
    __syncthreads();
    sl = red[0][0] + red[0][1] + red[0][2] + red[0][3];
    sr = red[1][0] + red[1][1] + red[1][2] + red[1][3];
    const float invl = 1.0f / sqrtf(fmaxf(sl, EPSF));
    const float invr = 1.0f / sqrtf(fmaxf(sr, EPSF));
    const float sL = 8.0f * invl;
    const float sR = 8.0f * invr;
    int pkL = __builtin_amdgcn_cvt_pk_fp8_f32(l.x * sL, l.y * sL, 0, false);
    pkL = __builtin_amdgcn_cvt_pk_fp8_f32(l.z * sL, l.w * sL, pkL, true);
    int pkR = __builtin_amdgcn_cvt_pk_fp8_f32(r.x * sR, r.y * sR, 0, false);
    pkR = __builtin_amdgcn_cvt_pk_fp8_f32(r.z * sR, r.w * sR, pkR, true);
    const int dst = row * Dk + 4 * t;   // plain row-major k-order
    *(unsigned*)(lnb8 + dst) = (unsigned)pkL;
    *(unsigned*)(rnb8 + dst) = (unsigned)pkR;
    if (t == 0) {
        const float d = red[2][0] + red[2][1] + red[2][2] + red[2][3];
        diag[row] = d * invl * invr;
        rowsum[row] = 0.f;
        colsum[row] = 0.f;
    }
}

// -------- Kernel 2: S = ln . rn^T via MX-scaled fp8 MFMA (scale == 1.0, bit-neutral) ----
// R3: revert to the PROVEN R1 geometry (128x256 block, 64x128 wave tile, 2 blocks/CU —
// R2's 256^2 tile collapsed occupancy to 1 wave/SIMD: MfmaUtil 12%, 53 us) and fix the
// sync structure instead:
//   * 3 LDS buffers (72 KB, still 2 blocks/CU), 2-tile-deep prefetch
//   * ONE barrier per iter: stage-issue moved AFTER the barrier, so the same barrier
//     orders "all reads of buf[(it+2)%3] done" before anyone restages it, and each
//     wave's counted vmcnt(6) before the barrier guarantees tile-it residency.
//   * counted vmcnt(6) in steady state (tile it+1 stays in flight across the barrier),
//     vmcnt(0) only on the last iteration.
// Full unroll makes all %3 buffer indices compile-time.
__global__ __launch_bounds__(256, 2)
void gemm_sm_kernel(const unsigned char* __restrict__ lnb8,
                    const unsigned char* __restrict__ rnb8,
                    const float* __restrict__ temp,
                    float* __restrict__ rowsum, float* __restrict__ colsum)
{
    __shared__ __align__(16) unsigned char As[3][128 * 64];   // 24 KB
    __shared__ __align__(16) unsigned char Bs[3][256 * 64];   // 48 KB

    const int tid = threadIdx.x;
    const int wave = tid >> 6;
    const int lane = tid & 63;
    const int bm0 = blockIdx.y * 128;
    const int bn0 = blockIdx.x * 256;

    // ---- staging: wave stages A rows [32w,32w+32) (2 insts) and B rows [64w,64w+64) (4 insts)
    const int srow = lane >> 2;
    const int sj = lane & 3;
    int goffA[2], lofsA[2];
    #pragma unroll
    for (int i = 0; i < 2; ++i) {
        const int rloc = wave * 32 + i * 16 + srow;
        goffA[i] = rloc * Dk + 16 * (sj ^ ((rloc >> 1) & 3));
        lofsA[i] = (wave * 32 + i * 16) * 64;
    }
    int goffB[4], lofsB[4];
    #pragma unroll
    for (int i = 0; i < 4; ++i) {
        const int rloc = wave * 64 + i * 16 + srow;
        goffB[i] = rloc * Dk + 16 * (sj ^ ((rloc >> 1) & 3));
        lofsB[i] = (wave * 64 + i * 16) * 64;
    }
    const unsigned char* baseA = lnb8 + (size_t)bm0 * Dk;
    const unsigned char* baseB = rnb8 + (size_t)bn0 * Dk;

    // ---- compute-side: wave tile 64x128 as 2x4 grid of 32x32 tiles
    const int wm = (wave & 1) * 64;
    const int wn = (wave >> 1) * 128;
    const int r32 = lane & 31;
    const int h = lane >> 5;     // k-half of the 64-byte K-tile
    int aoff[2][2], boff[4][2];
    #pragma unroll
    for (int mi = 0; mi < 2; ++mi) {
        const int row = wm + mi * 32 + r32;
        const int key = (row >> 1) & 3;
        aoff[mi][0] = row * 64 + 16 * ((2 * h) ^ key);
        aoff[mi][1] = row * 64 + 16 * ((2 * h + 1) ^ key);
    }
    #pragma unroll
    for (int ni = 0; ni < 4; ++ni) {
        const int row = wn + ni * 32 + r32;
        const int key = (row >> 1) & 3;
        boff[ni][0] = row * 64 + 16 * ((2 * h) ^ key);
        boff[ni][1] = row * 64 + 16 * ((2 * h + 1) ^ key);
    }

    f32x16 acc[2][4];
    #pragma unroll
    for (int mi = 0; mi < 2; ++mi)
        #pragma unroll
        for (int ni = 0; ni < 4; ++ni)
            #pragma unroll
            for (int r = 0; r < 16; ++r)
                acc[mi][ni][r] = 0.f;

    // prologue: stage tiles 0 and 1 into buffers 0 and 1 (12 loads in flight)
    #pragma unroll
    for (int b = 0; b < 2; ++b) {
        #pragma unroll
        for (int i = 0; i < 2; ++i) async_copy16(baseA + goffA[i] + b * 64, &As[b][lofsA[i]]);
        #pragma unroll
        for (int i = 0; i < 4; ++i) async_copy16(baseB + goffB[i] + b * 64, &Bs[b][lofsB[i]]);
    }

    #pragma unroll
    for (int it = 0; it < 16; ++it) {
        // steady state: 12 outstanding (tiles it, it+1); wait the oldest 6 -> tile it
        // resident, tile it+1 stays in flight across the barrier. Last iter: drain.
        if (it == 15)
            asm volatile("s_waitcnt vmcnt(0)\n\ts_barrier" ::: "memory");
        else
            asm volatile("s_waitcnt vmcnt(6)\n\ts_barrier" ::: "memory");
        // stage tile it+2 AFTER the barrier: all waves finished reading buf[(it+2)%3]
        // (their iter it-1 reads completed before they reached this barrier)
        if (it < 14) {
            const int nb = (it + 2) % 3;
            const int kn = (it + 2) * 64;
            #pragma unroll
            for (int i = 0; i < 2; ++i) async_copy16(baseA + goffA[i] + kn, &As[nb][lofsA[i]]);
            #pragma unroll
            for (int i = 0; i < 4; ++i) async_copy16(baseB + goffB[i] + kn, &Bs[nb][lofsB[i]]);
        }
        const int cur = it % 3;
        i32x8 af[2], bf[4];
        #pragma unroll
        for (int mi = 0; mi < 2; ++mi) {
            const i32x4 lo = *(const i32x4*)(&As[cur][aoff[mi][0]]);
            const i32x4 hi = *(const i32x4*)(&As[cur][aoff[mi][1]]);
            af[mi] = __builtin_shufflevector(lo, hi, 0, 1, 2, 3, 4, 5, 6, 7);
        }
        #pragma unroll
        for (int ni = 0; ni < 4; ++ni) {
            const i32x4 lo = *(const i32x4*)(&Bs[cur][boff[ni][0]]);
            const i32x4 hi = *(const i32x4*)(&Bs[cur][boff[ni][1]]);
            bf[ni] = __builtin_shufflevector(lo, hi, 0, 1, 2, 3, 4, 5, 6, 7);
        }
        #pragma unroll
        for (int mi = 0; mi < 2; ++mi)
            #pragma unroll
            for (int ni = 0; ni < 4; ++ni)
                acc[mi][ni] = __builtin_amdgcn_mfma_scale_f32_32x32x64_f8f6f4(
                    af[mi], bf[ni], acc[mi][ni],
                    0, 0,                       // cbsz=fp8(e4m3), blgp=fp8(e4m3)
                    0, 0x7f7f7f7f,              // A scale: E8M0 127 -> 2^0 = 1.0
                    0, 0x7f7f7f7f);             // B scale: 1.0
    }

    // epilogue: undo the 8x8 prescale (2^-6, exact), then p = exp(scale*s - scale)
    const float scale = __expf(temp[0]);
    const float dq = 0.015625f * scale;  // 2^-6 * scale
    #pragma unroll
    for (int mi = 0; mi < 2; ++mi)
        #pragma unroll
        for (int ni = 0; ni < 4; ++ni)
            #pragma unroll
            for (int r = 0; r < 16; ++r)
                acc[mi][ni][r] = __expf(dq * acc[mi][ni][r] - scale);

    // 32x32 C/D layout: col = lane&31, row = (reg&3) + 8*(reg>>2) + 4*(lane>>5)
    // row sums: reduce over cols (butterfly over the 32-lane column dimension)
    #pragma unroll
    for (int mi = 0; mi < 2; ++mi) {
        #pragma unroll
        for (int r = 0; r < 16; ++r) {
            float v = acc[mi][0][r] + acc[mi][1][r] + acc[mi][2][r] + acc[mi][3][r];
            v += __shfl_xor(v, 1);
            v += __shfl_xor(v, 2);
            v += __shfl_xor(v, 4);
            v += __shfl_xor(v, 8);
            v += __shfl_xor(v, 16);
            if (r32 == 0)
                atomicAdd(&rowsum[bm0 + wm + mi * 32 + (r & 3) + 8 * (r >> 2) + 4 * h], v);
        }
    }
    // col sums: each lane owns col r32; sum its 32 rows, then combine the two halves
    #pragma unroll
    for (int ni = 0; ni < 4; ++ni) {
        float v = 0.f;
        #pragma unroll
        for (int mi = 0; mi < 2; ++mi)
            #pragma unroll
            for (int r = 0; r < 16; ++r)
                v += acc[mi][ni][r];
        v += __shfl_xor(v, 32);
        if (h == 0)
            atomicAdd(&colsum[bn0 + wn + ni * 32 + r32], v);
    }
}

// -------- Kernel 3: final scalar loss --------
__global__ __launch_bounds__(256)
void loss_kernel(const float* __restrict__ diag, const float* __restrict__ rowsum,
                 const float* __restrict__ colsum, const float* __restrict__ temp,
                 float* __restrict__ out)
{
    const int t = threadIdx.x;
    const float scale = __expf(temp[0]);
    float dL = 0.f, dR = 0.f;
    for (int i = t; i < Bn; i += 256) {
        const float e = __expf(scale * (diag[i] - 1.0f));
        dL += e * __builtin_amdgcn_rcpf(rowsum[i]);
        dR += e * __builtin_amdgcn_rcpf(colsum[i]);
    }
    #pragma unroll
    for (int off = 1; off < 64; off <<= 1) {
        dL += __shfl_xor(dL, off);
        dR += __shfl_xor(dR, off);
    }
    __shared__ float rd[2][4];
    const int wave = t >> 6, lane = t & 63;
    if (lane == 0) { rd[0][wave] = dL; rd[1][wave] = dR; }
    __syncthreads();
    if (t == 0) {
        dL = rd[0][0] + rd[0][1] + rd[0][2] + rd[0][3];
        dR = rd[1][0] + rd[1][1] + rd[1][2] + rd[1][3];
        const float logeps = logf(EPSF);
        const float log1m = logf(1.0f - EPSF);
        const float lossL = -(dL * log1m + ((float)Bn - dL) * logeps);
        const float lossR = -(dR * log1m + ((float)Bn - dR) * logeps);
        out[0] = (lossL + lossR) * 0.5f / (float)Bn;
    }
}

extern "C" void kernel_launch(void* const* d_in, const int* in_sizes, int n_in,
                              void* d_out, int out_size, void* d_ws, size_t ws_size,
                              hipStream_t stream) {
    (void)in_sizes; (void)n_in; (void)out_size; (void)ws_size;
    const float* left = (const float*)d_in[0];
    const float* right = (const float*)d_in[1];
    const float* temp = (const float*)d_in[2];

    char* ws = (char*)d_ws;
    unsigned char* lnb8 = (unsigned char*)ws;                       // 4 MiB
    unsigned char* rnb8 = (unsigned char*)(ws + (size_t)Bn * Dk);   // 4 MiB
    float* diag = (float*)(ws + 2 * (size_t)Bn * Dk);
    float* rowsum = diag + Bn;
    float* colsum = rowsum + Bn;

    nrm_kernel<<<Bn, 256, 0, stream>>>((const float4*)left, (const float4*)right,
                                       lnb8, rnb8, diag, rowsum, colsum);
    dim3 g2(Bn / 256, Bn / 128);
    gemm_sm_kernel<<<g2, 256, 0, stream>>>(lnb8, rnb8, temp, rowsum, colsum);
    loss_kernel<<<1, 256, 0, stream>>>(diag, rowsum, colsum, temp, (float*)d_out);
}

// Round 4
// 130.101 us; speedup vs baseline: 1.7305x; 1.7305x over previous
//
#include <hip/hip_runtime.h>
#include <hip/hip_bf16.h>

#define Bn 4096
#define Dk 1024
#define EPSF 1e-7f
#define ATILE (256 * 64)   // one 256-row x 64-B K-tile of fp8 = 16 KB

typedef float f32x16 __attribute__((ext_vector_type(16)));
typedef int i32x4 __attribute__((ext_vector_type(4)));
typedef int i32x8 __attribute__((ext_vector_type(8)));

__device__ __forceinline__ void async_copy16(const void* g, void* l) {
    __builtin_amdgcn_global_load_lds((__attribute__((address_space(1))) void*)(uintptr_t)g,
                                     (__attribute__((address_space(3))) void*)l, 16, 0, 0);
}

// -------- Kernel 1: L2-normalize -> fp8 e4m3 (x8 prescale), PLAIN row-major layout ----
__global__ __launch_bounds__(256)
void nrm_kernel(const float4* __restrict__ left, const float4* __restrict__ right,
                unsigned char* __restrict__ lnb8, unsigned char* __restrict__ rnb8,
                float* __restrict__ diag, float* __restrict__ rowsum,
                float* __restrict__ colsum)
{
    const int row = blockIdx.x;
    const int t = threadIdx.x;
    const int idx = row * (Dk / 4) + t;
    const float4 l = left[idx];
    const float4 r = right[idx];
    float sl = l.x * l.x + l.y * l.y + l.z * l.z + l.w * l.w;
    float sr = r.x * r.x + r.y * r.y + r.z * r.z + r.w * r.w;
    float slr = l.x * r.x + l.y * r.y + l.z * r.z + l.w * r.w;
    #pragma unroll
    for (int off = 1; off < 64; off <<= 1) {
        sl += __shfl_xor(sl, off);
        sr += __shfl_xor(sr, off);
        slr += __shfl_xor(slr, off);
    }
    __shared__ float red[3][4];
    const int wave = t >> 6, lane = t & 63;
    if (lane == 0) { red[0][wave] = sl; red[1][wave] = sr; red[2][wave] = slr; }
    __syncthreads();
    sl = red[0][0] + red[0][1] + red[0][2] + red[0][3];
    sr = red[1][0] + red[1][1] + red[1][2] + red[1][3];
    const float invl = 1.0f / sqrtf(fmaxf(sl, EPSF));
    const float invr = 1.0f / sqrtf(fmaxf(sr, EPSF));
    const float sL = 8.0f * invl;
    const float sR = 8.0f * invr;
    int pkL = __builtin_amdgcn_cvt_pk_fp8_f32(l.x * sL, l.y * sL, 0, false);
    pkL = __builtin_amdgcn_cvt_pk_fp8_f32(l.z * sL, l.w * sL, pkL, true);
    int pkR = __builtin_amdgcn_cvt_pk_fp8_f32(r.x * sR, r.y * sR, 0, false);
    pkR = __builtin_amdgcn_cvt_pk_fp8_f32(r.z * sR, r.w * sR, pkR, true);
    const int dst = row * Dk + 4 * t;   // plain row-major k-order
    *(unsigned*)(lnb8 + dst) = (unsigned)pkL;
    *(unsigned*)(rnb8 + dst) = (unsigned)pkR;
    if (t == 0) {
        const float d = red[2][0] + red[2][1] + red[2][2] + red[2][3];
        diag[row] = d * invl * invr;
        rowsum[row] = 0.f;
        colsum[row] = 0.f;
    }
}

// -------- Kernel 2: 8-phase-style MX-fp8 GEMM + softmax-numerator reduction ----
// R4: template-geometry port (guide §5 8-phase): 256x256 tile, 512 thr / 8 waves
// (2M x 4N), wave tile 128x64 = 4x2 grid of 32x32 MX tiles (acc 128 regs -> ~200/wave,
// 2 waves/SIMD at launch_bounds(512,2) -- same occupancy as proven R1, no R2 collapse).
// 3 LDS buffers (96 KB, 1 block/CU), prefetch depth 2. Per K-tile: counted
// "s_waitcnt vmcnt(4)" + barrier (tile t+1 stays in flight; never drains mid-loop),
// then 4 phases: {ds_read cluster, 1 gload slice of tile t+2, s_barrier,
// lgkmcnt(0)+sched_barrier(0) [rule #18], setprio(1), 2 MFMA, setprio(0)}.
// K-loop is #pragma unroll 1 with a rotating buffer index -- R3's spill came from
// full-unroll register-pressure; all register arrays here are statically indexed.
__global__ __launch_bounds__(512, 2)
void gemm_sm_kernel(const unsigned char* __restrict__ lnb8,
                    const unsigned char* __restrict__ rnb8,
                    const float* __restrict__ temp,
                    float* __restrict__ rowsum, float* __restrict__ colsum)
{
    __shared__ __align__(16) unsigned char Ash[3 * ATILE];   // 48 KB
    __shared__ __align__(16) unsigned char Bsh[3 * ATILE];   // 48 KB

    const int tid = threadIdx.x;
    const int wave = tid >> 6;
    const int lane = tid & 63;
    const int bm0 = blockIdx.y * 256;
    const int bn0 = blockIdx.x * 256;

    // ---- staging: each wave stages A rows [32w,32w+32) and B rows [32w,32w+32)
    // (2 instr each; granule XOR-swizzle g^((row>>1)&3) on the global source)
    const int srow = lane >> 2;
    const int sj = lane & 3;
    int goffA[2], lofsA[2];
    #pragma unroll
    for (int i = 0; i < 2; ++i) {
        const int rloc = wave * 32 + i * 16 + srow;
        goffA[i] = rloc * Dk + 16 * (sj ^ ((rloc >> 1) & 3));
        lofsA[i] = (wave * 32 + i * 16) * 64;
    }
    const unsigned char* baseA = lnb8 + (size_t)bm0 * Dk;
    const unsigned char* baseB = rnb8 + (size_t)bn0 * Dk;

    // ---- compute-side: wave tile 128x64; wm=(wave&1)*128, wn=(wave>>1)*64
    const int wm = (wave & 1) * 128;
    const int wn = (wave >> 1) * 64;
    const int r32 = lane & 31;
    const int h = lane >> 5;     // k-half of the 64-byte K-tile
    int aoff[4][2], boff[2][2];
    #pragma unroll
    for (int mi = 0; mi < 4; ++mi) {
        const int row = wm + mi * 32 + r32;
        const int key = (row >> 1) & 3;
        aoff[mi][0] = row * 64 + 16 * ((2 * h) ^ key);
        aoff[mi][1] = row * 64 + 16 * ((2 * h + 1) ^ key);
    }
    #pragma unroll
    for (int ni = 0; ni < 2; ++ni) {
        const int row = wn + ni * 32 + r32;
        const int key = (row >> 1) & 3;
        boff[ni][0] = row * 64 + 16 * ((2 * h) ^ key);
        boff[ni][1] = row * 64 + 16 * ((2 * h + 1) ^ key);
    }

    f32x16 acc[4][2];
    #pragma unroll
    for (int mi = 0; mi < 4; ++mi)
        #pragma unroll
        for (int ni = 0; ni < 2; ++ni)
            #pragma unroll
            for (int r = 0; r < 16; ++r)
                acc[mi][ni][r] = 0.f;

    // prologue: stage tiles 0 and 1 (issue order = tile-major for vmcnt counting)
    #pragma unroll
    for (int b = 0; b < 2; ++b) {
        #pragma unroll
        for (int i = 0; i < 2; ++i)
            async_copy16(baseA + goffA[i] + b * 64, &Ash[b * ATILE + lofsA[i]]);
        #pragma unroll
        for (int i = 0; i < 2; ++i)
            async_copy16(baseB + goffA[i] + b * 64, &Bsh[b * ATILE + lofsA[i]]);
    }

    int cur = 0;
    #pragma unroll 1
    for (int t = 0; t < 16; ++t) {
        const int nb = (cur >= 1) ? (cur - 1) : 2;   // (cur+2)%3 without division
        // ---- K-tile boundary: own 4 loads of tile t done; t+1's stay in flight
        if (t == 15) asm volatile("s_waitcnt vmcnt(0)" ::: "memory");
        else         asm volatile("s_waitcnt vmcnt(4)" ::: "memory");
        __builtin_amdgcn_s_barrier();

        const unsigned char* At = &Ash[cur * ATILE];
        const unsigned char* Bt = &Bsh[cur * ATILE];
        unsigned char* An = &Ash[nb * ATILE];
        unsigned char* Bns = &Bsh[nb * ATILE];
        const int kn = (t + 2) * 64;
        const bool pf = (t < 14);

        i32x8 af0, af1, af2, af3, bf0, bf1;
        // ---- phase 0: read af0 + both B fragments; stage A slice 0 of tile t+2
        {
            const i32x4 alo = *(const i32x4*)(At + aoff[0][0]);
            const i32x4 ahi = *(const i32x4*)(At + aoff[0][1]);
            af0 = __builtin_shufflevector(alo, ahi, 0, 1, 2, 3, 4, 5, 6, 7);
            const i32x4 b0l = *(const i32x4*)(Bt + boff[0][0]);
            const i32x4 b0h = *(const i32x4*)(Bt + boff[0][1]);
            bf0 = __builtin_shufflevector(b0l, b0h, 0, 1, 2, 3, 4, 5, 6, 7);
            const i32x4 b1l = *(const i32x4*)(Bt + boff[1][0]);
            const i32x4 b1h = *(const i32x4*)(Bt + boff[1][1]);
            bf1 = __builtin_shufflevector(b1l, b1h, 0, 1, 2, 3, 4, 5, 6, 7);
            if (pf) async_copy16(baseA + goffA[0] + kn, An + lofsA[0]);
        }
        __builtin_amdgcn_s_barrier();
        asm volatile("s_waitcnt lgkmcnt(0)" ::: "memory");
        __builtin_amdgcn_sched_barrier(0);
        __builtin_amdgcn_s_setprio(1);
        acc[0][0] = __builtin_amdgcn_mfma_scale_f32_32x32x64_f8f6f4(
            af0, bf0, acc[0][0], 0, 0, 0, 0x7f7f7f7f, 0, 0x7f7f7f7f);
        acc[0][1] = __builtin_amdgcn_mfma_scale_f32_32x32x64_f8f6f4(
            af0, bf1, acc[0][1], 0, 0, 0, 0x7f7f7f7f, 0, 0x7f7f7f7f);
        __builtin_amdgcn_s_setprio(0);

        // ---- phase 1: read af1; stage A slice 1
        {
            const i32x4 alo = *(const i32x4*)(At + aoff[1][0]);
            const i32x4 ahi = *(const i32x4*)(At + aoff[1][1]);
            af1 = __builtin_shufflevector(alo, ahi, 0, 1, 2, 3, 4, 5, 6, 7);
            if (pf) async_copy16(baseA + goffA[1] + kn, An + lofsA[1]);
        }
        __builtin_amdgcn_s_barrier();
        asm volatile("s_waitcnt lgkmcnt(0)" ::: "memory");
        __builtin_amdgcn_sched_barrier(0);
        __builtin_amdgcn_s_setprio(1);
        acc[1][0] = __builtin_amdgcn_mfma_scale_f32_32x32x64_f8f6f4(
            af1, bf0, acc[1][0], 0, 0, 0, 0x7f7f7f7f, 0, 0x7f7f7f7f);
        acc[1][1] = __builtin_amdgcn_mfma_scale_f32_32x32x64_f8f6f4(
            af1, bf1, acc[1][1], 0, 0, 0, 0x7f7f7f7f, 0, 0x7f7f7f7f);
        __builtin_amdgcn_s_setprio(0);

        // ---- phase 2: read af2; stage B slice 0
        {
            const i32x4 alo = *(const i32x4*)(At + aoff[2][0]);
            const i32x4 ahi = *(const i32x4*)(At + aoff[2][1]);
            af2 = __builtin_shufflevector(alo, ahi, 0, 1, 2, 3, 4, 5, 6, 7);
            if (pf) async_copy16(baseB + goffA[0] + kn, Bns + lofsA[0]);
        }
        __builtin_amdgcn_s_barrier();
        asm volatile("s_waitcnt lgkmcnt(0)" ::: "memory");
        __builtin_amdgcn_sched_barrier(0);
        __builtin_amdgcn_s_setprio(1);
        acc[2][0] = __builtin_amdgcn_mfma_scale_f32_32x32x64_f8f6f4(
            af2, bf0, acc[2][0], 0, 0, 0, 0x7f7f7f7f, 0, 0x7f7f7f7f);
        acc[2][1] = __builtin_amdgcn_mfma_scale_f32_32x32x64_f8f6f4(
            af2, bf1, acc[2][1], 0, 0, 0, 0x7f7f7f7f, 0, 0x7f7f7f7f);
        __builtin_amdgcn_s_setprio(0);

        // ---- phase 3: read af3; stage B slice 1
        {
            const i32x4 alo = *(const i32x4*)(At + aoff[3][0]);
            const i32x4 ahi = *(const i32x4*)(At + aoff[3][1]);
            af3 = __builtin_shufflevector(alo, ahi, 0, 1, 2, 3, 4, 5, 6, 7);
            if (pf) async_copy16(baseB + goffA[1] + kn, Bns + lofsA[1]);
        }
        __builtin_amdgcn_s_barrier();
        asm volatile("s_waitcnt lgkmcnt(0)" ::: "memory");
        __builtin_amdgcn_sched_barrier(0);
        __builtin_amdgcn_s_setprio(1);
        acc[3][0] = __builtin_amdgcn_mfma_scale_f32_32x32x64_f8f6f4(
            af3, bf0, acc[3][0], 0, 0, 0, 0x7f7f7f7f, 0, 0x7f7f7f7f);
        acc[3][1] = __builtin_amdgcn_mfma_scale_f32_32x32x64_f8f6f4(
            af3, bf1, acc[3][1], 0, 0, 0, 0x7f7f7f7f, 0, 0x7f7f7f7f);
        __builtin_amdgcn_s_setprio(0);

        cur = (cur == 2) ? 0 : cur + 1;
    }

    // epilogue: undo the 8x8 prescale (2^-6, exact), then p = exp(scale*s - scale)
    const float scale = __expf(temp[0]);
    const float dq = 0.015625f * scale;  // 2^-6 * scale
    #pragma unroll
    for (int mi = 0; mi < 4; ++mi)
        #pragma unroll
        for (int ni = 0; ni < 2; ++ni)
            #pragma unroll
            for (int r = 0; r < 16; ++r)
                acc[mi][ni][r] = __expf(dq * acc[mi][ni][r] - scale);

    // 32x32 C/D layout: col = lane&31, row = (reg&3) + 8*(reg>>2) + 4*(lane>>5)
    // row sums: reduce over cols (butterfly over the 32-lane column dimension)
    #pragma unroll
    for (int mi = 0; mi < 4; ++mi) {
        #pragma unroll
        for (int r = 0; r < 16; ++r) {
            float v = acc[mi][0][r] + acc[mi][1][r];
            v += __shfl_xor(v, 1);
            v += __shfl_xor(v, 2);
            v += __shfl_xor(v, 4);
            v += __shfl_xor(v, 8);
            v += __shfl_xor(v, 16);
            if (r32 == 0)
                atomicAdd(&rowsum[bm0 + wm + mi * 32 + (r & 3) + 8 * (r >> 2) + 4 * h], v);
        }
    }
    // col sums: each lane owns col r32; sum its 32 rows, then combine the two halves
    #pragma unroll
    for (int ni = 0; ni < 2; ++ni) {
        float v = 0.f;
        #pragma unroll
        for (int mi = 0; mi < 4; ++mi)
            #pragma unroll
            for (int r = 0; r < 16; ++r)
                v += acc[mi][ni][r];
        v += __shfl_xor(v, 32);
        if (h == 0)
            atomicAdd(&colsum[bn0 + wn + ni * 32 + r32], v);
    }
}

// -------- Kernel 3: final scalar loss --------
__global__ __launch_bounds__(256)
void loss_kernel(const float* __restrict__ diag, const float* __restrict__ rowsum,
                 const float* __restrict__ colsum, const float* __restrict__ temp,
                 float* __restrict__ out)
{
    const int t = threadIdx.x;
    const float scale = __expf(temp[0]);
    float dL = 0.f, dR = 0.f;
    for (int i = t; i < Bn; i += 256) {
        const float e = __expf(scale * (diag[i] - 1.0f));
        dL += e * __builtin_amdgcn_rcpf(rowsum[i]);
        dR += e * __builtin_amdgcn_rcpf(colsum[i]);
    }
    #pragma unroll
    for (int off = 1; off < 64; off <<= 1) {
        dL += __shfl_xor(dL, off);
        dR += __shfl_xor(dR, off);
    }
    __shared__ float rd[2][4];
    const int wave = t >> 6, lane = t & 63;
    if (lane == 0) { rd[0][wave] = dL; rd[1][wave] = dR; }
    __syncthreads();
    if (t == 0) {
        dL = rd[0][0] + rd[0][1] + rd[0][2] + rd[0][3];
        dR = rd[1][0] + rd[1][1] + rd[1][2] + rd[1][3];
        const float logeps = logf(EPSF);
        const float log1m = logf(1.0f - EPSF);
        const float lossL = -(dL * log1m + ((float)Bn - dL) * logeps);
        const float lossR = -(dR * log1m + ((float)Bn - dR) * logeps);
        out[0] = (lossL + lossR) * 0.5f / (float)Bn;
    }
}

extern "C" void kernel_launch(void* const* d_in, const int* in_sizes, int n_in,
                              void* d_out, int out_size, void* d_ws, size_t ws_size,
                              hipStream_t stream) {
    (void)in_sizes; (void)n_in; (void)out_size; (void)ws_size;
    const float* left = (const float*)d_in[0];
    const float* right = (const float*)d_in[1];
    const float* temp = (const float*)d_in[2];

    char* ws = (char*)d_ws;
    unsigned char* lnb8 = (unsigned char*)ws;                       // 4 MiB
    unsigned char* rnb8 = (unsigned char*)(ws + (size_t)Bn * Dk);   // 4 MiB
    float* diag = (float*)(ws + 2 * (size_t)Bn * Dk);
    float* rowsum = diag + Bn;
    float* colsum = rowsum + Bn;

    nrm_kernel<<<Bn, 256, 0, stream>>>((const float4*)left, (const float4*)right,
                                       lnb8, rnb8, diag, rowsum, colsum);
    dim3 g2(Bn / 256, Bn / 256);
    gemm_sm_kernel<<<g2, 512, 0, stream>>>(lnb8, rnb8, temp, rowsum, colsum);
    loss_kernel<<<1, 256, 0, stream>>>(diag, rowsum, colsum, temp, (float*)d_out);
}

// Round 5
// 129.430 us; speedup vs baseline: 1.7395x; 1.0052x over previous
//
#include <hip/hip_runtime.h>
#include <hip/hip_bf16.h>

#define Bn 4096
#define Dk 1024
#define EPSF 1e-7f

typedef float f32x16 __attribute__((ext_vector_type(16)));
typedef int i32x4 __attribute__((ext_vector_type(4)));
typedef int i32x8 __attribute__((ext_vector_type(8)));

__device__ __forceinline__ void async_copy16(const void* g, void* l) {
    __builtin_amdgcn_global_load_lds((__attribute__((address_space(1))) void*)(uintptr_t)g,
                                     (__attribute__((address_space(3))) void*)l, 16, 0, 0);
}

// -------- Kernel 1: L2-normalize -> fp8 e4m3 (x8 prescale), PLAIN row-major layout ----
__global__ __launch_bounds__(256)
void nrm_kernel(const float4* __restrict__ left, const float4* __restrict__ right,
                unsigned char* __restrict__ lnb8, unsigned char* __restrict__ rnb8,
                float* __restrict__ diag, float* __restrict__ rowsum,
                float* __restrict__ colsum)
{
    const int row = blockIdx.x;
    const int t = threadIdx.x;
    const int idx = row * (Dk / 4) + t;
    const float4 l = left[idx];
    const float4 r = right[idx];
    float sl = l.x * l.x + l.y * l.y + l.z * l.z + l.w * l.w;
    float sr = r.x * r.x + r.y * r.y + r.z * r.z + r.w * r.w;
    float slr = l.x * r.x + l.y * r.y + l.z * r.z + l.w * r.w;
    #pragma unroll
    for (int off = 1; off < 64; off <<= 1) {
        sl += __shfl_xor(sl, off);
        sr += __shfl_xor(sr, off);
        slr += __shfl_xor(slr, off);
    }
    __shared__ float red[3][4];
    const int wave = t >> 6, lane = t & 63;
    if (lane == 0) { red[0][wave] = sl; red[1][wave] = sr; red[2][wave] = slr; }
    __syncthreads();
    sl = red[0][0] + red[0][1] + red[0][2] + red[0][3];
    sr = red[1][0] + red[1][1] + red[1][2] + red[1][3];
    const float invl = 1.0f / sqrtf(fmaxf(sl, EPSF));
    const float invr = 1.0f / sqrtf(fmaxf(sr, EPSF));
    const float sL = 8.0f * invl;
    const float sR = 8.0f * invr;
    int pkL = __builtin_amdgcn_cvt_pk_fp8_f32(l.x * sL, l.y * sL, 0, false);
    pkL = __builtin_amdgcn_cvt_pk_fp8_f32(l.z * sL, l.w * sL, pkL, true);
    int pkR = __builtin_amdgcn_cvt_pk_fp8_f32(r.x * sR, r.y * sR, 0, false);
    pkR = __builtin_amdgcn_cvt_pk_fp8_f32(r.z * sR, r.w * sR, pkR, true);
    const int dst = row * Dk + 4 * t;   // plain row-major k-order
    *(unsigned*)(lnb8 + dst) = (unsigned)pkL;
    *(unsigned*)(rnb8 + dst) = (unsigned)pkR;
    if (t == 0) {
        const float d = red[2][0] + red[2][1] + red[2][2] + red[2][3];
        diag[row] = d * invl * invr;
        rowsum[row] = 0.f;
        colsum[row] = 0.f;
    }
}

// -------- Kernel 2: MX-fp8 GEMM, A via LDS ping-pong, B GLOBAL->REGISTERS ----
// R5: R1's proven skeleton (128x256 block, 64x128 wave tile, 2 blocks/CU, 2 barriers,
// counted vmcnt, dummy-wrap last iter) with ONE change: the B operand skips LDS.
// Rationale (R1..R4 calibration): per-iter cost = MFMA + ~3170 cyc fixed, of which the
// LDS-read phase (12 ds_read_b128/wave, B = 8 of them) is the largest removable part.
// Each lane's B fragment is 32 contiguous global bytes (granules 2h,2h+1 - the staging
// XOR and the read XOR cancel, verified algebraically: LDS[g]=glob[g^key] read at g^key);
// 2 lanes cover each 64B line -> fully-coalesced L2-resident reads, prefetched one full
// iteration (~2500 cyc) ahead of use, far beyond L2 (~200) / HBM (~900) latency.
// LDS shrinks to 16 KB (A only); LDS-phase 1150 -> ~380 cyc/CU/iter.
// vmcnt bookkeeping at iter top: queue = {A(t):2, B(t):8, A(t+1):2} -> vmcnt(10)
// retires A(t); the compiler's own waitcnt (which models global_load_lds in the same
// counter) covers B(t) before the MFMAs.
__global__ __launch_bounds__(256, 2)
void gemm_sm_kernel(const unsigned char* __restrict__ lnb8,
                    const unsigned char* __restrict__ rnb8,
                    const float* __restrict__ temp,
                    float* __restrict__ rowsum, float* __restrict__ colsum)
{
    __shared__ __align__(16) unsigned char As[2][128 * 64];   // 16 KB total

    const int tid = threadIdx.x;
    const int wave = tid >> 6;
    const int lane = tid & 63;
    const int bm0 = blockIdx.y * 128;
    const int bn0 = blockIdx.x * 256;

    // ---- A staging: wave stages rows [32w,32w+32) (2 insts), granule XOR-swizzle
    const int srow = lane >> 2;
    const int sj = lane & 3;
    int goffA[2], lofsA[2];
    #pragma unroll
    for (int i = 0; i < 2; ++i) {
        const int rloc = wave * 32 + i * 16 + srow;
        goffA[i] = rloc * Dk + 16 * (sj ^ ((rloc >> 1) & 3));
        lofsA[i] = (wave * 32 + i * 16) * 64;
    }
    const unsigned char* baseA = lnb8 + (size_t)bm0 * Dk;

    // ---- compute-side: wave tile 64x128 as 2x4 grid of 32x32 tiles
    const int wm = (wave & 1) * 64;
    const int wn = (wave >> 1) * 128;
    const int r32 = lane & 31;
    const int h = lane >> 5;     // k-half of the 64-byte K-tile
    int aoff[2][2];
    #pragma unroll
    for (int mi = 0; mi < 2; ++mi) {
        const int row = wm + mi * 32 + r32;
        const int key = (row >> 1) & 3;
        aoff[mi][0] = row * 64 + 16 * ((2 * h) ^ key);
        aoff[mi][1] = row * 64 + 16 * ((2 * h + 1) ^ key);
    }
    // B: per-lane global base (row-major fp8), 32 contiguous bytes per fragment
    const unsigned char* bbase[4];
    #pragma unroll
    for (int ni = 0; ni < 4; ++ni)
        bbase[ni] = rnb8 + (size_t)(bn0 + wn + ni * 32 + r32) * Dk + 32 * h;

    f32x16 acc[2][4];
    #pragma unroll
    for (int mi = 0; mi < 2; ++mi)
        #pragma unroll
        for (int ni = 0; ni < 4; ++ni)
            #pragma unroll
            for (int r = 0; r < 16; ++r)
                acc[mi][ni][r] = 0.f;

    // prologue: stage A tile 0 (2 loads), then load B tile 0 into registers (8 loads)
    #pragma unroll
    for (int i = 0; i < 2; ++i) async_copy16(baseA + goffA[i], &As[0][lofsA[i]]);
    i32x8 bf[4];
    #pragma unroll
    for (int ni = 0; ni < 4; ++ni) {
        const i32x4 lo = *(const i32x4*)(bbase[ni]);
        const i32x4 hi = *(const i32x4*)(bbase[ni] + 16);
        bf[ni] = __builtin_shufflevector(lo, hi, 0, 1, 2, 3, 4, 5, 6, 7);
    }

    #pragma unroll 2
    for (int it = 0; it < 16; ++it) {
        const int cur = it & 1;
        const int nxt = cur ^ 1;
        const int knext = ((it + 1) & 15) * 64;   // wraps on last iter (dummy reload)
        // stage A tile it+1 (2 loads)
        #pragma unroll
        for (int i = 0; i < 2; ++i) async_copy16(baseA + goffA[i] + knext, &As[nxt][lofsA[i]]);
        // queue: A(it):2, B(it):8, A(it+1):2 -> retire oldest 2 = A(it) resident
        asm volatile("s_waitcnt vmcnt(10)\n\ts_barrier" ::: "memory");
        // A fragments from LDS
        i32x8 af[2];
        #pragma unroll
        for (int mi = 0; mi < 2; ++mi) {
            const i32x4 lo = *(const i32x4*)(&As[cur][aoff[mi][0]]);
            const i32x4 hi = *(const i32x4*)(&As[cur][aoff[mi][1]]);
            af[mi] = __builtin_shufflevector(lo, hi, 0, 1, 2, 3, 4, 5, 6, 7);
        }
        // prefetch B tile it+1 into fresh registers (in flight across the MFMA cluster)
        i32x8 nbf[4];
        #pragma unroll
        for (int ni = 0; ni < 4; ++ni) {
            const i32x4 lo = *(const i32x4*)(bbase[ni] + knext);
            const i32x4 hi = *(const i32x4*)(bbase[ni] + knext + 16);
            nbf[ni] = __builtin_shufflevector(lo, hi, 0, 1, 2, 3, 4, 5, 6, 7);
        }
        // MFMA cluster (compiler inserts the counted vmcnt for B(it) residency)
        #pragma unroll
        for (int mi = 0; mi < 2; ++mi)
            #pragma unroll
            for (int ni = 0; ni < 4; ++ni)
                acc[mi][ni] = __builtin_amdgcn_mfma_scale_f32_32x32x64_f8f6f4(
                    af[mi], bf[ni], acc[mi][ni],
                    0, 0,                       // cbsz=fp8(e4m3), blgp=fp8(e4m3)
                    0, 0x7f7f7f7f,              // A scale: E8M0 127 -> 2^0 = 1.0
                    0, 0x7f7f7f7f);             // B scale: 1.0
        // execution-only barrier: everyone done reading A[cur] before it is restaged
        asm volatile("s_barrier" ::: "memory");
        #pragma unroll
        for (int ni = 0; ni < 4; ++ni) bf[ni] = nbf[ni];
    }

    // epilogue: undo the 8x8 prescale (2^-6, exact), then p = exp(scale*s - scale)
    const float scale = __expf(temp[0]);
    const float dq = 0.015625f * scale;  // 2^-6 * scale
    #pragma unroll
    for (int mi = 0; mi < 2; ++mi)
        #pragma unroll
        for (int ni = 0; ni < 4; ++ni)
            #pragma unroll
            for (int r = 0; r < 16; ++r)
                acc[mi][ni][r] = __expf(dq * acc[mi][ni][r] - scale);

    // 32x32 C/D layout: col = lane&31, row = (reg&3) + 8*(reg>>2) + 4*(lane>>5)
    // row sums: reduce over cols (butterfly over the 32-lane column dimension)
    #pragma unroll
    for (int mi = 0; mi < 2; ++mi) {
        #pragma unroll
        for (int r = 0; r < 16; ++r) {
            float v = acc[mi][0][r] + acc[mi][1][r] + acc[mi][2][r] + acc[mi][3][r];
            v += __shfl_xor(v, 1);
            v += __shfl_xor(v, 2);
            v += __shfl_xor(v, 4);
            v += __shfl_xor(v, 8);
            v += __shfl_xor(v, 16);
            if (r32 == 0)
                atomicAdd(&rowsum[bm0 + wm + mi * 32 + (r & 3) + 8 * (r >> 2) + 4 * h], v);
        }
    }
    // col sums: each lane owns col r32; sum its 32 rows, then combine the two halves
    #pragma unroll
    for (int ni = 0; ni < 4; ++ni) {
        float v = 0.f;
        #pragma unroll
        for (int mi = 0; mi < 2; ++mi)
            #pragma unroll
            for (int r = 0; r < 16; ++r)
                v += acc[mi][ni][r];
        v += __shfl_xor(v, 32);
        if (h == 0)
            atomicAdd(&colsum[bn0 + wn + ni * 32 + r32], v);
    }
}

// -------- Kernel 3: final scalar loss --------
__global__ __launch_bounds__(256)
void loss_kernel(const float* __restrict__ diag, const float* __restrict__ rowsum,
                 const float* __restrict__ colsum, const float* __restrict__ temp,
                 float* __restrict__ out)
{
    const int t = threadIdx.x;
    const float scale = __expf(temp[0]);
    float dL = 0.f, dR = 0.f;
    for (int i = t; i < Bn; i += 256) {
        const float e = __expf(scale * (diag[i] - 1.0f));
        dL += e * __builtin_amdgcn_rcpf(rowsum[i]);
        dR += e * __builtin_amdgcn_rcpf(colsum[i]);
    }
    #pragma unroll
    for (int off = 1; off < 64; off <<= 1) {
        dL += __shfl_xor(dL, off);
        dR += __shfl_xor(dR, off);
    }
    __shared__ float rd[2][4];
    const int wave = t >> 6, lane = t & 63;
    if (lane == 0) { rd[0][wave] = dL; rd[1][wave] = dR; }
    __syncthreads();
    if (t == 0) {
        dL = rd[0][0] + rd[0][1] + rd[0][2] + rd[0][3];
        dR = rd[1][0] + rd[1][1] + rd[1][2] + rd[1][3];
        const float logeps = logf(EPSF);
        const float log1m = logf(1.0f - EPSF);
        const float lossL = -(dL * log1m + ((float)Bn - dL) * logeps);
        const float lossR = -(dR * log1m + ((float)Bn - dR) * logeps);
        out[0] = (lossL + lossR) * 0.5f / (float)Bn;
    }
}

extern "C" void kernel_launch(void* const* d_in, const int* in_sizes, int n_in,
                              void* d_out, int out_size, void* d_ws, size_t ws_size,
                              hipStream_t stream) {
    (void)in_sizes; (void)n_in; (void)out_size; (void)ws_size;
    const float* left = (const float*)d_in[0];
    const float* right = (const float*)d_in[1];
    const float* temp = (const float*)d_in[2];

    char* ws = (char*)d_ws;
    unsigned char* lnb8 = (unsigned char*)ws;                       // 4 MiB
    unsigned char* rnb8 = (unsigned char*)(ws + (size_t)Bn * Dk);   // 4 MiB
    float* diag = (float*)(ws + 2 * (size_t)Bn * Dk);
    float* rowsum = diag + Bn;
    float* colsum = rowsum + Bn;

    nrm_kernel<<<Bn, 256, 0, stream>>>((const float4*)left, (const float4*)right,
                                       lnb8, rnb8, diag, rowsum, colsum);
    dim3 g2(Bn / 256, Bn / 128);
    gemm_sm_kernel<<<g2, 256, 0, stream>>>(lnb8, rnb8, temp, rowsum, colsum);
    loss_kernel<<<1, 256, 0, stream>>>(diag, rowsum, colsum, temp, (float*)d_out);
}

// Round 6
// 123.037 us; speedup vs baseline: 1.8298x; 1.0520x over previous
//
#include <hip/hip_runtime.h>
#include <hip/hip_bf16.h>

#define Bn 4096
#define Dk 1024
#define EPSF 1e-7f

typedef float f32x16 __attribute__((ext_vector_type(16)));
typedef int i32x4 __attribute__((ext_vector_type(4)));
typedef int i32x8 __attribute__((ext_vector_type(8)));

__device__ __forceinline__ void async_copy16(const void* g, void* l) {
    __builtin_amdgcn_global_load_lds((__attribute__((address_space(1))) void*)(uintptr_t)g,
                                     (__attribute__((address_space(3))) void*)l, 16, 0, 0);
}

// -------- Kernel 1: L2-normalize -> fp8 e4m3 (x8 prescale), PLAIN row-major layout ----
__global__ __launch_bounds__(256)
void nrm_kernel(const float4* __restrict__ left, const float4* __restrict__ right,
                unsigned char* __restrict__ lnb8, unsigned char* __restrict__ rnb8,
                float* __restrict__ diag, float* __restrict__ rowsum,
                float* __restrict__ colsum, unsigned int* __restrict__ ctr)
{
    const int row = blockIdx.x;
    const int t = threadIdx.x;
    const int idx = row * (Dk / 4) + t;
    const float4 l = left[idx];
    const float4 r = right[idx];
    float sl = l.x * l.x + l.y * l.y + l.z * l.z + l.w * l.w;
    float sr = r.x * r.x + r.y * r.y + r.z * r.z + r.w * r.w;
    float slr = l.x * r.x + l.y * r.y + l.z * r.z + l.w * r.w;
    #pragma unroll
    for (int off = 1; off < 64; off <<= 1) {
        sl += __shfl_xor(sl, off);
        sr += __shfl_xor(sr, off);
        slr += __shfl_xor(slr, off);
    }
    __shared__ float red[3][4];
    const int wave = t >> 6, lane = t & 63;
    if (lane == 0) { red[0][wave] = sl; red[1][wave] = sr; red[2][wave] = slr; }
    __syncthreads();
    sl = red[0][0] + red[0][1] + red[0][2] + red[0][3];
    sr = red[1][0] + red[1][1] + red[1][2] + red[1][3];
    const float invl = 1.0f / sqrtf(fmaxf(sl, EPSF));
    const float invr = 1.0f / sqrtf(fmaxf(sr, EPSF));
    const float sL = 8.0f * invl;
    const float sR = 8.0f * invr;
    int pkL = __builtin_amdgcn_cvt_pk_fp8_f32(l.x * sL, l.y * sL, 0, false);
    pkL = __builtin_amdgcn_cvt_pk_fp8_f32(l.z * sL, l.w * sL, pkL, true);
    int pkR = __builtin_amdgcn_cvt_pk_fp8_f32(r.x * sR, r.y * sR, 0, false);
    pkR = __builtin_amdgcn_cvt_pk_fp8_f32(r.z * sR, r.w * sR, pkR, true);
    const int dst = row * Dk + 4 * t;   // plain row-major k-order
    *(unsigned*)(lnb8 + dst) = (unsigned)pkL;
    *(unsigned*)(rnb8 + dst) = (unsigned)pkR;
    if (t == 0) {
        const float d = red[2][0] + red[2][1] + red[2][2] + red[2][3];
        diag[row] = d * invl * invr;
        rowsum[row] = 0.f;
        colsum[row] = 0.f;
        if (row == 0) *ctr = 0u;   // reset last-block counter (ordered before gemm dispatch)
    }
}

// -------- Kernel 2: MX-fp8 GEMM (R1 geometry) + 1-barrier/iter 3-buffer loop
//          + FUSED final loss via last-block pattern ----
// R6: R1's proven geometry (128x256 block, 64x128 wave tile, 2 blocks/CU) with the
// R3 sync design executed WITHOUT the full-unroll spill that sank R3 (WRITE_SIZE
// 259 MB scratch there; here #pragma unroll 1 + rotating indices, R4-proven ~100 VGPR):
//   * 3 LDS buffers (72 KB -> still 2 blocks/CU), 2-tile-deep prefetch
//   * ONE barrier per iter. Ordering: stage of tile it+2 into buf[(it+2)%3] is issued
//     AFTER iter it's barrier; all waves' reads of that buffer (tile it-1) completed
//     before they arrived at this barrier (their ds_reads retire before their MFMAs).
//   * counted vmcnt(6): tile it resident, tile it+1 stays in flight across the barrier;
//     vmcnt(0) only on the last iteration.
// Loss fusion: after the block's rowsum/colsum atomics + __syncthreads, tid0 fences and
// increments a device counter; the block observing 511 (the last to finish) computes the
// scalar loss with agent-scope atomic loads. No block ever waits on an unfinished block,
// so no co-residency assumption (Guideline 16-safe).
__global__ __launch_bounds__(256, 2)
void gemm_sm_kernel(const unsigned char* __restrict__ lnb8,
                    const unsigned char* __restrict__ rnb8,
                    const float* __restrict__ temp,
                    float* __restrict__ rowsum, float* __restrict__ colsum,
                    const float* __restrict__ diag, float* __restrict__ out,
                    unsigned int* __restrict__ ctr)
{
    __shared__ __align__(16) unsigned char As[3][128 * 64];   // 24 KB
    __shared__ __align__(16) unsigned char Bs[3][256 * 64];   // 48 KB

    const int tid = threadIdx.x;
    const int wave = tid >> 6;
    const int lane = tid & 63;
    const int bm0 = blockIdx.y * 128;
    const int bn0 = blockIdx.x * 256;

    // ---- staging: wave stages A rows [32w,32w+32) (2 insts) and B rows [64w,64w+64) (4 insts)
    const int srow = lane >> 2;
    const int sj = lane & 3;
    int goffA[2], lofsA[2];
    #pragma unroll
    for (int i = 0; i < 2; ++i) {
        const int rloc = wave * 32 + i * 16 + srow;
        goffA[i] = rloc * Dk + 16 * (sj ^ ((rloc >> 1) & 3));
        lofsA[i] = (wave * 32 + i * 16) * 64;
    }
    int goffB[4], lofsB[4];
    #pragma unroll
    for (int i = 0; i < 4; ++i) {
        const int rloc = wave * 64 + i * 16 + srow;
        goffB[i] = rloc * Dk + 16 * (sj ^ ((rloc >> 1) & 3));
        lofsB[i] = (wave * 64 + i * 16) * 64;
    }
    const unsigned char* baseA = lnb8 + (size_t)bm0 * Dk;
    const unsigned char* baseB = rnb8 + (size_t)bn0 * Dk;

    // ---- compute-side: wave tile 64x128 as 2x4 grid of 32x32 tiles
    const int wm = (wave & 1) * 64;
    const int wn = (wave >> 1) * 128;
    const int r32 = lane & 31;
    const int h = lane >> 5;     // k-half of the 64-byte K-tile
    int aoff[2][2], boff[4][2];
    #pragma unroll
    for (int mi = 0; mi < 2; ++mi) {
        const int row = wm + mi * 32 + r32;
        const int key = (row >> 1) & 3;
        aoff[mi][0] = row * 64 + 16 * ((2 * h) ^ key);
        aoff[mi][1] = row * 64 + 16 * ((2 * h + 1) ^ key);
    }
    #pragma unroll
    for (int ni = 0; ni < 4; ++ni) {
        const int row = wn + ni * 32 + r32;
        const int key = (row >> 1) & 3;
        boff[ni][0] = row * 64 + 16 * ((2 * h) ^ key);
        boff[ni][1] = row * 64 + 16 * ((2 * h + 1) ^ key);
    }

    f32x16 acc[2][4];
    #pragma unroll
    for (int mi = 0; mi < 2; ++mi)
        #pragma unroll
        for (int ni = 0; ni < 4; ++ni)
            #pragma unroll
            for (int r = 0; r < 16; ++r)
                acc[mi][ni][r] = 0.f;

    // prologue: stage tiles 0 and 1 into buffers 0 and 1 (12 loads in flight)
    #pragma unroll
    for (int b = 0; b < 2; ++b) {
        #pragma unroll
        for (int i = 0; i < 2; ++i) async_copy16(baseA + goffA[i] + b * 64, &As[b][lofsA[i]]);
        #pragma unroll
        for (int i = 0; i < 4; ++i) async_copy16(baseB + goffB[i] + b * 64, &Bs[b][lofsB[i]]);
    }

    int cur = 0;
    #pragma unroll 1
    for (int it = 0; it < 16; ++it) {
        // steady state: 12 outstanding (tiles it, it+1); retire the oldest 6 -> tile it
        // resident, tile it+1 stays in flight across the barrier. Last iter: drain.
        if (it == 15) asm volatile("s_waitcnt vmcnt(0)\n\ts_barrier" ::: "memory");
        else         asm volatile("s_waitcnt vmcnt(6)\n\ts_barrier" ::: "memory");
        // stage tile it+2 AFTER the barrier into buf[(it+2)%3] (= buf[(it-1)%3]):
        // every wave's reads of that buffer completed before it reached this barrier.
        const int nb = (cur == 0) ? 2 : cur - 1;
        if (it < 14) {
            const int kn = (it + 2) * 64;
            #pragma unroll
            for (int i = 0; i < 2; ++i) async_copy16(baseA + goffA[i] + kn, &As[nb][lofsA[i]]);
            #pragma unroll
            for (int i = 0; i < 4; ++i) async_copy16(baseB + goffB[i] + kn, &Bs[nb][lofsB[i]]);
        }
        const unsigned char* At = As[cur];
        const unsigned char* Bt = Bs[cur];
        i32x8 af[2], bf[4];
        #pragma unroll
        for (int mi = 0; mi < 2; ++mi) {
            const i32x4 lo = *(const i32x4*)(At + aoff[mi][0]);
            const i32x4 hi = *(const i32x4*)(At + aoff[mi][1]);
            af[mi] = __builtin_shufflevector(lo, hi, 0, 1, 2, 3, 4, 5, 6, 7);
        }
        #pragma unroll
        for (int ni = 0; ni < 4; ++ni) {
            const i32x4 lo = *(const i32x4*)(Bt + boff[ni][0]);
            const i32x4 hi = *(const i32x4*)(Bt + boff[ni][1]);
            bf[ni] = __builtin_shufflevector(lo, hi, 0, 1, 2, 3, 4, 5, 6, 7);
        }
        #pragma unroll
        for (int mi = 0; mi < 2; ++mi)
            #pragma unroll
            for (int ni = 0; ni < 4; ++ni)
                acc[mi][ni] = __builtin_amdgcn_mfma_scale_f32_32x32x64_f8f6f4(
                    af[mi], bf[ni], acc[mi][ni],
                    0, 0,                       // cbsz=fp8(e4m3), blgp=fp8(e4m3)
                    0, 0x7f7f7f7f,              // A scale: E8M0 127 -> 2^0 = 1.0
                    0, 0x7f7f7f7f);             // B scale: 1.0
        cur = (cur == 2) ? 0 : cur + 1;
    }

    // epilogue: undo the 8x8 prescale (2^-6, exact), then p = exp(scale*s - scale)
    const float scale = __expf(temp[0]);
    const float dq = 0.015625f * scale;  // 2^-6 * scale
    #pragma unroll
    for (int mi = 0; mi < 2; ++mi)
        #pragma unroll
        for (int ni = 0; ni < 4; ++ni)
            #pragma unroll
            for (int r = 0; r < 16; ++r)
                acc[mi][ni][r] = __expf(dq * acc[mi][ni][r] - scale);

    // 32x32 C/D layout: col = lane&31, row = (reg&3) + 8*(reg>>2) + 4*(lane>>5)
    // row sums: reduce over cols (butterfly over the 32-lane column dimension)
    #pragma unroll
    for (int mi = 0; mi < 2; ++mi) {
        #pragma unroll
        for (int r = 0; r < 16; ++r) {
            float v = acc[mi][0][r] + acc[mi][1][r] + acc[mi][2][r] + acc[mi][3][r];
            v += __shfl_xor(v, 1);
            v += __shfl_xor(v, 2);
            v += __shfl_xor(v, 4);
            v += __shfl_xor(v, 8);
            v += __shfl_xor(v, 16);
            if (r32 == 0)
                atomicAdd(&rowsum[bm0 + wm + mi * 32 + (r & 3) + 8 * (r >> 2) + 4 * h], v);
        }
    }
    // col sums: each lane owns col r32; sum its 32 rows, then combine the two halves
    #pragma unroll
    for (int ni = 0; ni < 4; ++ni) {
        float v = 0.f;
        #pragma unroll
        for (int mi = 0; mi < 2; ++mi)
            #pragma unroll
            for (int r = 0; r < 16; ++r)
                v += acc[mi][ni][r];
        v += __shfl_xor(v, 32);
        if (h == 0)
            atomicAdd(&colsum[bn0 + wn + ni * 32 + r32], v);
    }

    // ---- fused loss: last block to finish computes the scalar ----
    __syncthreads();                       // all this block's atomics drained (vmcnt(0))
    __shared__ unsigned int lastflag;
    if (tid == 0) {
        __threadfence();                   // release our sums device-wide
        const unsigned int nblocks = gridDim.x * gridDim.y;
        unsigned int old = __hip_atomic_fetch_add(ctr, 1u, __ATOMIC_ACQ_REL,
                                                  __HIP_MEMORY_SCOPE_AGENT);
        lastflag = (old == nblocks - 1u) ? 1u : 0u;
    }
    __syncthreads();
    if (lastflag) {
        __threadfence();                   // acquire: see all blocks' sums
        float dL = 0.f, dR = 0.f;
        for (int i = tid; i < Bn; i += 256) {
            const float rs = __hip_atomic_load(&rowsum[i], __ATOMIC_RELAXED,
                                               __HIP_MEMORY_SCOPE_AGENT);
            const float cs = __hip_atomic_load(&colsum[i], __ATOMIC_RELAXED,
                                               __HIP_MEMORY_SCOPE_AGENT);
            const float e = __expf(scale * (diag[i] - 1.0f));
            dL += e * __builtin_amdgcn_rcpf(rs);
            dR += e * __builtin_amdgcn_rcpf(cs);
        }
        #pragma unroll
        for (int off = 1; off < 64; off <<= 1) {
            dL += __shfl_xor(dL, off);
            dR += __shfl_xor(dR, off);
        }
        __shared__ float rd[2][4];
        if (lane == 0) { rd[0][wave] = dL; rd[1][wave] = dR; }
        __syncthreads();
        if (tid == 0) {
            dL = rd[0][0] + rd[0][1] + rd[0][2] + rd[0][3];
            dR = rd[1][0] + rd[1][1] + rd[1][2] + rd[1][3];
            const float logeps = logf(EPSF);
            const float log1m = logf(1.0f - EPSF);
            const float lossL = -(dL * log1m + ((float)Bn - dL) * logeps);
            const float lossR = -(dR * log1m + ((float)Bn - dR) * logeps);
            out[0] = (lossL + lossR) * 0.5f / (float)Bn;
        }
    }
}

extern "C" void kernel_launch(void* const* d_in, const int* in_sizes, int n_in,
                              void* d_out, int out_size, void* d_ws, size_t ws_size,
                              hipStream_t stream) {
    (void)in_sizes; (void)n_in; (void)out_size; (void)ws_size;
    const float* left = (const float*)d_in[0];
    const float* right = (const float*)d_in[1];
    const float* temp = (const float*)d_in[2];

    char* ws = (char*)d_ws;
    unsigned char* lnb8 = (unsigned char*)ws;                       // 4 MiB
    unsigned char* rnb8 = (unsigned char*)(ws + (size_t)Bn * Dk);   // 4 MiB
    float* diag = (float*)(ws + 2 * (size_t)Bn * Dk);
    float* rowsum = diag + Bn;
    float* colsum = rowsum + Bn;
    unsigned int* ctr = (unsigned int*)(colsum + Bn);

    nrm_kernel<<<Bn, 256, 0, stream>>>((const float4*)left, (const float4*)right,
                                       lnb8, rnb8, diag, rowsum, colsum, ctr);
    dim3 g2(Bn / 256, Bn / 128);
    gemm_sm_kernel<<<g2, 256, 0, stream>>>(lnb8, rnb8, temp, rowsum, colsum,
                                           diag, (float*)d_out, ctr);
}

// Round 8
// 113.265 us; speedup vs baseline: 1.9877x; 1.0863x over previous
//
#include <hip/hip_runtime.h>
#include <hip/hip_bf16.h>

#define Bn 4096
#define Dk 1024
#define EPSF 1e-7f

typedef float f32x16 __attribute__((ext_vector_type(16)));
typedef int i32x4 __attribute__((ext_vector_type(4)));
typedef int i32x8 __attribute__((ext_vector_type(8)));

__device__ __forceinline__ void async_copy16(const void* g, void* l) {
    __builtin_amdgcn_global_load_lds((__attribute__((address_space(1))) void*)(uintptr_t)g,
                                     (__attribute__((address_space(3))) void*)l, 16, 0, 0);
}

// -------- Kernel 1: L2-normalize -> fp8 e4m3 (x8 prescale), PLAIN row-major layout ----
__global__ __launch_bounds__(256)
void nrm_kernel(const float4* __restrict__ left, const float4* __restrict__ right,
                unsigned char* __restrict__ lnb8, unsigned char* __restrict__ rnb8,
                float* __restrict__ diag, float* __restrict__ rowsum,
                float* __restrict__ colsum, unsigned int* __restrict__ ctr)
{
    const int row = blockIdx.x;
    const int t = threadIdx.x;
    const int idx = row * (Dk / 4) + t;
    const float4 l = left[idx];
    const float4 r = right[idx];
    float sl = l.x * l.x + l.y * l.y + l.z * l.z + l.w * l.w;
    float sr = r.x * r.x + r.y * r.y + r.z * r.z + r.w * r.w;
    float slr = l.x * r.x + l.y * r.y + l.z * r.z + l.w * r.w;
    #pragma unroll
    for (int off = 1; off < 64; off <<= 1) {
        sl += __shfl_xor(sl, off);
        sr += __shfl_xor(sr, off);
        slr += __shfl_xor(slr, off);
    }
    __shared__ float red[3][4];
    const int wave = t >> 6, lane = t & 63;
    if (lane == 0) { red[0][wave] = sl; red[1][wave] = sr; red[2][wave] = slr; }
    __syncthreads();
    sl = red[0][0] + red[0][1] + red[0][2] + red[0][3];
    sr = red[1][0] + red[1][1] + red[1][2] + red[1][3];
    const float invl = 1.0f / sqrtf(fmaxf(sl, EPSF));
    const float invr = 1.0f / sqrtf(fmaxf(sr, EPSF));
    const float sL = 8.0f * invl;
    const float sR = 8.0f * invr;
    int pkL = __builtin_amdgcn_cvt_pk_fp8_f32(l.x * sL, l.y * sL, 0, false);
    pkL = __builtin_amdgcn_cvt_pk_fp8_f32(l.z * sL, l.w * sL, pkL, true);
    int pkR = __builtin_amdgcn_cvt_pk_fp8_f32(r.x * sR, r.y * sR, 0, false);
    pkR = __builtin_amdgcn_cvt_pk_fp8_f32(r.z * sR, r.w * sR, pkR, true);
    const int dst = row * Dk + 4 * t;   // plain row-major k-order
    *(unsigned*)(lnb8 + dst) = (unsigned)pkL;
    *(unsigned*)(rnb8 + dst) = (unsigned)pkR;
    if (t == 0) {
        const float d = red[2][0] + red[2][1] + red[2][2] + red[2][3];
        diag[row] = d * invl * invr;
        rowsum[row] = 0.f;
        colsum[row] = 0.f;
        if (row == 0) *ctr = 0u;   // reset last-block counter (ordered before gemm dispatch)
    }
}

// -------- Kernel 2: MX-fp8 GEMM — EXACT R1 K-loop (the proven optimum) + fence-free
//          fused loss tail ----
// Six structural experiments (R2..R6) all regressed vs this loop (49-60 us vs ~29):
// R2 256^2 occupancy-collapse; R3 full-unroll spill; R4 barrier-per-phase; R5 strided
// B-gather (32 cache lines/instr); R6 runtime buffer indices -> compiler must assume
// ds_read aliases the in-flight global_load_lds and drains vmcnt(0) per iter. The
// unroll-2 ping-pong with COMPILE-TIME buffer indices is what lets the counted
// "s_waitcnt vmcnt(6); s_barrier" actually keep the prefetch in flight. DO NOT
// restructure this loop.
// Loss fusion (kept from R6, fences REMOVED): each block's rowsum/colsum atomicAdds are
// device-scope atomics drained by __syncthreads (vmcnt) before tid0's ACQ_REL
// agent-scope fetch_add on ctr; the last block acquire-syncs with all releases and
// reads the sums via agent-scope atomic loads (atomics bypass the non-coherent L2s, so
// no __threadfence = no 512x L2-writeback — the suspected prev-session R12 pathology).
__global__ __launch_bounds__(256, 2)
void gemm_sm_kernel(const unsigned char* __restrict__ lnb8,
                    const unsigned char* __restrict__ rnb8,
                    const float* __restrict__ temp,
                    float* __restrict__ rowsum, float* __restrict__ colsum,
                    const float* __restrict__ diag, float* __restrict__ out,
                    unsigned int* __restrict__ ctr)
{
    __shared__ __align__(16) unsigned char As[2][128 * 64];
    __shared__ __align__(16) unsigned char Bs[2][256 * 64];

    const int tid = threadIdx.x;
    const int wave = tid >> 6;
    const int lane = tid & 63;
    const int bm0 = blockIdx.y * 128;
    const int bn0 = blockIdx.x * 256;

    // ---- staging: wave stages A rows [32w,32w+32) (2 insts) and B rows [64w,64w+64) (4 insts)
    const int srow = lane >> 2;
    const int sj = lane & 3;
    int goffA[2], lofsA[2];
    #pragma unroll
    for (int i = 0; i < 2; ++i) {
        const int rloc = wave * 32 + i * 16 + srow;
        goffA[i] = rloc * Dk + 16 * (sj ^ ((rloc >> 1) & 3));
        lofsA[i] = (wave * 32 + i * 16) * 64;
    }
    int goffB[4], lofsB[4];
    #pragma unroll
    for (int i = 0; i < 4; ++i) {
        const int rloc = wave * 64 + i * 16 + srow;
        goffB[i] = rloc * Dk + 16 * (sj ^ ((rloc >> 1) & 3));
        lofsB[i] = (wave * 64 + i * 16) * 64;
    }
    const unsigned char* baseA = lnb8 + (size_t)bm0 * Dk;
    const unsigned char* baseB = rnb8 + (size_t)bn0 * Dk;

    // ---- compute-side: wave tile 64x128 as 2x4 grid of 32x32 tiles
    const int wm = (wave & 1) * 64;
    const int wn = (wave >> 1) * 128;
    const int r32 = lane & 31;
    const int h = lane >> 5;     // k-half of the 64-byte K-tile
    int aoff[2][2], boff[4][2];
    #pragma unroll
    for (int mi = 0; mi < 2; ++mi) {
        const int row = wm + mi * 32 + r32;
        const int key = (row >> 1) & 3;
        aoff[mi][0] = row * 64 + 16 * ((2 * h) ^ key);
        aoff[mi][1] = row * 64 + 16 * ((2 * h + 1) ^ key);
    }
    #pragma unroll
    for (int ni = 0; ni < 4; ++ni) {
        const int row = wn + ni * 32 + r32;
        const int key = (row >> 1) & 3;
        boff[ni][0] = row * 64 + 16 * ((2 * h) ^ key);
        boff[ni][1] = row * 64 + 16 * ((2 * h + 1) ^ key);
    }

    f32x16 acc[2][4];
    #pragma unroll
    for (int mi = 0; mi < 2; ++mi)
        #pragma unroll
        for (int ni = 0; ni < 4; ++ni)
            #pragma unroll
            for (int r = 0; r < 16; ++r)
                acc[mi][ni][r] = 0.f;

    // prologue: stage tile 0 into buffer 0
    #pragma unroll
    for (int i = 0; i < 2; ++i) async_copy16(baseA + goffA[i], &As[0][lofsA[i]]);
    #pragma unroll
    for (int i = 0; i < 4; ++i) async_copy16(baseB + goffB[i], &Bs[0][lofsB[i]]);

    #pragma unroll 2
    for (int it = 0; it < 16; ++it) {
        const int cur = it & 1;
        const int nxt = cur ^ 1;
        const int knext = ((it + 1) & 15) * 64;   // wraps on last iter (dummy reload)
        #pragma unroll
        for (int i = 0; i < 2; ++i) async_copy16(baseA + goffA[i] + knext, &As[nxt][lofsA[i]]);
        #pragma unroll
        for (int i = 0; i < 4; ++i) async_copy16(baseB + goffB[i] + knext, &Bs[nxt][lofsB[i]]);
        // wait only the PREVIOUS tile's 6 loads; this iter's prefetch stays in flight
        asm volatile("s_waitcnt vmcnt(6)\n\ts_barrier" ::: "memory");
        i32x8 af[2], bf[4];
        #pragma unroll
        for (int mi = 0; mi < 2; ++mi) {
            const i32x4 lo = *(const i32x4*)(&As[cur][aoff[mi][0]]);
            const i32x4 hi = *(const i32x4*)(&As[cur][aoff[mi][1]]);
            af[mi] = __builtin_shufflevector(lo, hi, 0, 1, 2, 3, 4, 5, 6, 7);
        }
        #pragma unroll
        for (int ni = 0; ni < 4; ++ni) {
            const i32x4 lo = *(const i32x4*)(&Bs[cur][boff[ni][0]]);
            const i32x4 hi = *(const i32x4*)(&Bs[cur][boff[ni][1]]);
            bf[ni] = __builtin_shufflevector(lo, hi, 0, 1, 2, 3, 4, 5, 6, 7);
        }
        #pragma unroll
        for (int mi = 0; mi < 2; ++mi)
            #pragma unroll
            for (int ni = 0; ni < 4; ++ni)
                acc[mi][ni] = __builtin_amdgcn_mfma_scale_f32_32x32x64_f8f6f4(
                    af[mi], bf[ni], acc[mi][ni],
                    0, 0,                       // cbsz=fp8(e4m3), blgp=fp8(e4m3)
                    0, 0x7f7f7f7f,              // A scale: E8M0 127 -> 2^0 = 1.0
                    0, 0x7f7f7f7f);             // B scale: 1.0
        // execution-only barrier: everyone done reading `cur` before it is restaged
        asm volatile("s_barrier" ::: "memory");
    }

    // epilogue: undo the 8x8 prescale (2^-6, exact), then p = exp(scale*s - scale)
    const float scale = __expf(temp[0]);
    const float dq = 0.015625f * scale;  // 2^-6 * scale
    #pragma unroll
    for (int mi = 0; mi < 2; ++mi)
        #pragma unroll
        for (int ni = 0; ni < 4; ++ni)
            #pragma unroll
            for (int r = 0; r < 16; ++r)
                acc[mi][ni][r] = __expf(dq * acc[mi][ni][r] - scale);

    // 32x32 C/D layout: col = lane&31, row = (reg&3) + 8*(reg>>2) + 4*(lane>>5)
    // row sums: reduce over cols (butterfly over the 32-lane column dimension)
    #pragma unroll
    for (int mi = 0; mi < 2; ++mi) {
        #pragma unroll
        for (int r = 0; r < 16; ++r) {
            float v = acc[mi][0][r] + acc[mi][1][r] + acc[mi][2][r] + acc[mi][3][r];
            v += __shfl_xor(v, 1);
            v += __shfl_xor(v, 2);
            v += __shfl_xor(v, 4);
            v += __shfl_xor(v, 8);
            v += __shfl_xor(v, 16);
            if (r32 == 0)
                atomicAdd(&rowsum[bm0 + wm + mi * 32 + (r & 3) + 8 * (r >> 2) + 4 * h], v);
        }
    }
    // col sums: each lane owns col r32; sum its 32 rows, then combine the two halves
    #pragma unroll
    for (int ni = 0; ni < 4; ++ni) {
        float v = 0.f;
        #pragma unroll
        for (int mi = 0; mi < 2; ++mi)
            #pragma unroll
            for (int r = 0; r < 16; ++r)
                v += acc[mi][ni][r];
        v += __shfl_xor(v, 32);
        if (h == 0)
            atomicAdd(&colsum[bn0 + wn + ni * 32 + r32], v);
    }

    // ---- fused loss: last block to finish computes the scalar (fence-free) ----
    __syncthreads();                       // drains this block's atomics (vmcnt)
    __shared__ unsigned int lastflag;
    if (tid == 0) {
        const unsigned int nblocks = gridDim.x * gridDim.y;
        unsigned int old = __hip_atomic_fetch_add(ctr, 1u, __ATOMIC_ACQ_REL,
                                                  __HIP_MEMORY_SCOPE_AGENT);
        lastflag = (old == nblocks - 1u) ? 1u : 0u;
    }
    __syncthreads();
    if (lastflag) {
        float dL = 0.f, dR = 0.f;
        for (int i = tid; i < Bn; i += 256) {
            const float rs = __hip_atomic_load(&rowsum[i], __ATOMIC_RELAXED,
                                               __HIP_MEMORY_SCOPE_AGENT);
            const float cs = __hip_atomic_load(&colsum[i], __ATOMIC_RELAXED,
                                               __HIP_MEMORY_SCOPE_AGENT);
            const float e = __expf(scale * (diag[i] - 1.0f));
            dL += e * __builtin_amdgcn_rcpf(rs);
            dR += e * __builtin_amdgcn_rcpf(cs);
        }
        #pragma unroll
        for (int off = 1; off < 64; off <<= 1) {
            dL += __shfl_xor(dL, off);
            dR += __shfl_xor(dR, off);
        }
        __shared__ float rd[2][4];
        if (lane == 0) { rd[0][wave] = dL; rd[1][wave] = dR; }
        __syncthreads();
        if (tid == 0) {
            dL = rd[0][0] + rd[0][1] + rd[0][2] + rd[0][3];
            dR = rd[1][0] + rd[1][1] + rd[1][2] + rd[1][3];
            const float logeps = logf(EPSF);
            const float log1m = logf(1.0f - EPSF);
            const float lossL = -(dL * log1m + ((float)Bn - dL) * logeps);
            const float lossR = -(dR * log1m + ((float)Bn - dR) * logeps);
            out[0] = (lossL + lossR) * 0.5f / (float)Bn;
        }
    }
}

extern "C" void kernel_launch(void* const* d_in, const int* in_sizes, int n_in,
                              void* d_out, int out_size, void* d_ws, size_t ws_size,
                              hipStream_t stream) {
    (void)in_sizes; (void)n_in; (void)out_size; (void)ws_size;
    const float* left = (const float*)d_in[0];
    const float* right = (const float*)d_in[1];
    const float* temp = (const float*)d_in[2];

    char* ws = (char*)d_ws;
    unsigned char* lnb8 = (unsigned char*)ws;                       // 4 MiB
    unsigned char* rnb8 = (unsigned char*)(ws + (size_t)Bn * Dk);   // 4 MiB
    float* diag = (float*)(ws + 2 * (size_t)Bn * Dk);
    float* rowsum = diag + Bn;
    float* colsum = rowsum + Bn;
    unsigned int* ctr = (unsigned int*)(colsum + Bn);

    nrm_kernel<<<Bn, 256, 0, stream>>>((const float4*)left, (const float4*)right,
                                       lnb8, rnb8, diag, rowsum, colsum, ctr);
    dim3 g2(Bn / 256, Bn / 128);
    gemm_sm_kernel<<<g2, 256, 0, stream>>>(lnb8, rnb8, temp, rowsum, colsum,
                                           diag, (float*)d_out, ctr);
}